// Round 4
// baseline (11305.213 us; speedup 1.0000x reference)
//
#include <hip/hip_runtime.h>
#include <stdint.h>
#include <stddef.h>

#define HDIM 200
#define FDIM 48
#define ADIM 6
#define BTOT 4096
#define NSTEP 119
#define CTXM1 9   // CONTEXT_FRAMES-1
#define MROWS 32  // batch rows per pair-group (each block computes all 32 rows, half the units)

typedef __attribute__((ext_vector_type(8))) short short8;
typedef __attribute__((ext_vector_type(4))) float floatx4;

// ws layout (bytes)
#define OFF_W1P 0u        // 52*8*64*8 u16
#define OFF_W2P 425984u   // 52*14*64*8 u16
#define OFF_W3P 1171456u  // 13*8*64*8 u16
#define OFF_W4P 1277952u  // 3*7*64*8 u16
#define OFF_B1  1299456u  // 832 f32
#define OFF_B2  1302784u
#define OFF_B3  1306112u  // 208 f32
#define OFF_B4  1306944u  // 48 f32
#define OFF_FLG 1307136u  // 256 i32
#define OFF_H1S 1308160u  // [128][32][104] u32 (bf16 pairs)
#define OFF_H2S 3012096u
#define OFF_O3S 4716032u  // end 6419968

__device__ __forceinline__ unsigned short f2bf(float f) {
  unsigned int u = __float_as_uint(f);
  u += 0x7FFFu + ((u >> 16) & 1u);
  return (unsigned short)(u >> 16);
}
__device__ __forceinline__ float sigm(float x) { return 1.0f / (1.0f + __expf(-x)); }
__device__ __forceinline__ float tanh_(float x) { return 1.0f - 2.0f / (1.0f + __expf(2.0f * x)); }

// ---------------- weight/bias packing (fp32 -> bf16, gate-major) + flag zeroing ----------------
__global__ void actp_pack(
    const float* __restrict__ Wih1, const float* __restrict__ Whh1,
    const float* __restrict__ bih1, const float* __restrict__ bhh1,
    const float* __restrict__ Wih2, const float* __restrict__ Whh2,
    const float* __restrict__ bih2, const float* __restrict__ bhh2,
    const float* __restrict__ fc1w, const float* __restrict__ fc1b,
    const float* __restrict__ fc2w, const float* __restrict__ fc2b,
    unsigned short* __restrict__ W1p, unsigned short* __restrict__ W2p,
    unsigned short* __restrict__ W3p, unsigned short* __restrict__ W4p,
    float* __restrict__ b1, float* __restrict__ b2,
    float* __restrict__ b3, float* __restrict__ b4,
    int* __restrict__ flags) {
  int g = blockIdx.x * blockDim.x + threadIdx.x;
  if (g < 26624) {  // W1p: K=256 (inp 48 | h1 200 | pad 8), 8 chunks, 52 tiles
    int lane = g & 63, tc = g >> 6;
    int chunk = tc & 7, tile = tc >> 3;
    int p = tile * 16 + (lane & 15);
    int gate = p / 208, u = p - gate * 208;
    int srow = gate * 200 + u;
    int kb = chunk * 32 + (lane >> 4) * 8;
    unsigned short* d = W1p + (size_t)g * 8;
#pragma unroll
    for (int j = 0; j < 8; ++j) {
      int k = kb + j;
      float v = 0.f;
      if (u < 200) {
        if (k < 48) v = Wih1[srow * 48 + k];
        else if (k < 248) v = Whh1[srow * 200 + (k - 48)];
      }
      d[j] = f2bf(v);
    }
  } else if (g < 73216) {  // W2p: K=448 (h1|tiled|h2), 14 chunks, 52 tiles
    int g2 = g - 26624;
    int lane = g2 & 63, tc = g2 >> 6;
    int chunk = tc % 14, tile = tc / 14;
    int p = tile * 16 + (lane & 15);
    int gate = p / 208, u = p - gate * 208;
    int srow = gate * 200 + u;
    int kb = chunk * 32 + (lane >> 4) * 8;
    unsigned short* d = W2p + (size_t)g2 * 8;
#pragma unroll
    for (int j = 0; j < 8; ++j) {
      int k = kb + j;
      float v = 0.f;
      if (u < 200) v = (k < 248) ? Wih2[srow * 248 + k] : Whh2[srow * 200 + (k - 248)];
      d[j] = f2bf(v);
    }
  } else if (g < 79872) {  // W3p: fc1_w N 200->208, K 248->256
    int g3 = g - 73216;
    int lane = g3 & 63, tc = g3 >> 6;
    int chunk = tc & 7, tile = tc >> 3;
    int p = tile * 16 + (lane & 15);
    int kb = chunk * 32 + (lane >> 4) * 8;
    unsigned short* d = W3p + (size_t)g3 * 8;
#pragma unroll
    for (int j = 0; j < 8; ++j) {
      int k = kb + j;
      float v = (p < 200 && k < 248) ? fc1w[p * 248 + k] : 0.f;
      d[j] = f2bf(v);
    }
  } else if (g < 81216) {  // W4p: fc2_w N=48, K 200->224
    int g4 = g - 79872;
    int lane = g4 & 63, tc = g4 >> 6;
    int chunk = tc % 7, tile = tc / 7;
    int p = tile * 16 + (lane & 15);
    int kb = chunk * 32 + (lane >> 4) * 8;
    unsigned short* d = W4p + (size_t)g4 * 8;
#pragma unroll
    for (int j = 0; j < 8; ++j) {
      int k = kb + j;
      float v = (k < 200) ? fc2w[p * 200 + k] : 0.f;
      d[j] = f2bf(v);
    }
  } else if (g < 83136) {  // biases, gate-major padded
    int i = g - 81216;
    if (i < 832) {
      int gate = i / 208, u = i - gate * 208;
      b1[i] = (u < 200) ? (bih1[gate * 200 + u] + bhh1[gate * 200 + u]) : 0.f;
    } else if (i < 1664) {
      int p = i - 832;
      int gate = p / 208, u = p - gate * 208;
      b2[p] = (u < 200) ? (bih2[gate * 200 + u] + bhh2[gate * 200 + u]) : 0.f;
    } else if (i < 1872) {
      int p = i - 1664;
      b3[p] = (p < 200) ? fc1b[p] : 0.f;
    } else {
      int p = i - 1872;
      b4[p] = fc2b[p];
    }
  } else if (g < 83392) {  // zero pair-sync flags
    flags[g - 83136] = 0;
  }
}

// ---------------- main persistent kernel ----------------
// 256 blocks x 512 threads, 1 block/CU (LDS 136KB forces it; grid == CU count => all resident).
// Pair (b, b^128) shares rows [32*grp, 32*grp+32); role = b>>7 owns half the unit tiles.
// role0: LSTM1 tiles [0,7), LSTM2 [0,6), FC1 [0,7); role1: complements. FC2 replicated.
__global__ __launch_bounds__(512, 2) void actp_main(
    const float* __restrict__ tact, const float* __restrict__ acts,
    const unsigned short* __restrict__ W1p, const unsigned short* __restrict__ W2p,
    const unsigned short* __restrict__ W3p, const unsigned short* __restrict__ W4p,
    const float* __restrict__ b1, const float* __restrict__ b2,
    const float* __restrict__ b3, const float* __restrict__ b4,
    int* __restrict__ flags, uint32_t* __restrict__ h1s,
    uint32_t* __restrict__ h2s, uint32_t* __restrict__ o3s,
    float* __restrict__ out) {
  __shared__ unsigned short x1[MROWS][264];  // [inp 0:48 | h1 48:248 | pad]
  __shared__ unsigned short x2[MROWS][456];  // [h1 0:200 | tiled 200:248 | h2 248:448 | pad]
  __shared__ unsigned short x3[MROWS][264];  // [h2 0:200 | inp 200:248 | pad]
  __shared__ unsigned short x4[MROWS][232];  // [out3 0:208 | pad]
  __shared__ float c1s[MROWS][228];
  __shared__ float c2s[MROWS][228];

  const int tid = threadIdx.x;
  const int wv = tid >> 6;
  const int lane = tid & 63;
  const int n16 = lane & 15;
  const int qd = lane >> 4;
  const int bid = (int)blockIdx.x;
  const int role = bid >> 7;
  const int grp = bid & 127;
  const int peer = bid ^ 128;
  const int row0 = grp * MROWS;
  // tile ownership
  const int l1_lo = role ? 7 : 0, l1_hi = role ? 13 : 7;
  const int l2_lo = role ? 6 : 0, l2_hi = role ? 13 : 6;
  const int f1_lo = role ? 7 : 0, f1_hi = role ? 13 : 7;
  int sctr = 0;

  // ---- init ----
  for (int i = tid; i < MROWS * 264; i += 512) { (&x1[0][0])[i] = 0; (&x3[0][0])[i] = 0; }
  for (int i = tid; i < MROWS * 456; i += 512) (&x2[0][0])[i] = 0;
  for (int i = tid; i < MROWS * 232; i += 512) (&x4[0][0])[i] = 0;
  for (int i = tid; i < MROWS * 228; i += 512) { (&c1s[0][0])[i] = 0.f; (&c2s[0][0])[i] = 0.f; }
  for (int i = tid; i < MROWS * 12; i += 512) {  // inp(0) = tact[0]
    int r = i / 12, f0 = (i % 12) * 4;
    const float* src = &tact[((size_t)(row0 + r)) * FDIM + f0];
#pragma unroll
    for (int j = 0; j < 4; ++j) {
      unsigned short v = f2bf(src[j]);
      x1[r][f0 + j] = v;
      x3[r][HDIM + f0 + j] = v;
    }
  }
  for (int i = tid; i < MROWS * 12; i += 512) {  // tiled(0) = tile([acts[1]|acts[0]],4)
    int r = i / 12, a = i % 12;
    float vf = (a < ADIM) ? acts[((size_t)BTOT + row0 + r) * ADIM + a]
                          : acts[((size_t)(row0 + r)) * ADIM + (a - ADIM)];
    unsigned short v = f2bf(vf);
    unsigned short* d = &x2[r][HDIM];
    d[a] = v; d[12 + a] = v; d[24 + a] = v; d[36 + a] = v;
  }
  __syncthreads();

  for (int t = 0; t < NSTEP; ++t) {
    // ================= Phase A: LSTM1 (own tiles), K=256 =================
    {
      int ut = l1_lo + wv;
      if (ut < l1_hi) {
        short8 A0[8], A1[8];
#pragma unroll
        for (int c = 0; c < 8; ++c) {
          A0[c] = *(const short8*)&x1[n16][c * 32 + qd * 8];
          A1[c] = *(const short8*)&x1[16 + n16][c * 32 + qd * 8];
        }
        floatx4 ai0, ai1, af0, af1, ag0, ag1, ao0, ao1;
        {
          float b = b1[(0 * 13 + ut) * 16 + n16]; ai0 = {b, b, b, b}; ai1 = ai0;
          b = b1[(1 * 13 + ut) * 16 + n16]; af0 = {b, b, b, b}; af1 = af0;
          b = b1[(2 * 13 + ut) * 16 + n16]; ag0 = {b, b, b, b}; ag1 = ag0;
          b = b1[(3 * 13 + ut) * 16 + n16]; ao0 = {b, b, b, b}; ao1 = ao0;
        }
        const short8* wi = (const short8*)W1p + (size_t)(0 * 13 + ut) * 8 * 64 + lane;
        const short8* wf = (const short8*)W1p + (size_t)(1 * 13 + ut) * 8 * 64 + lane;
        const short8* wg = (const short8*)W1p + (size_t)(2 * 13 + ut) * 8 * 64 + lane;
        const short8* wo = (const short8*)W1p + (size_t)(3 * 13 + ut) * 8 * 64 + lane;
#pragma unroll
        for (int c = 0; c < 8; ++c) {
          short8 w = wi[c * 64];
          ai0 = __builtin_amdgcn_mfma_f32_16x16x32_bf16(A0[c], w, ai0, 0, 0, 0);
          ai1 = __builtin_amdgcn_mfma_f32_16x16x32_bf16(A1[c], w, ai1, 0, 0, 0);
          w = wf[c * 64];
          af0 = __builtin_amdgcn_mfma_f32_16x16x32_bf16(A0[c], w, af0, 0, 0, 0);
          af1 = __builtin_amdgcn_mfma_f32_16x16x32_bf16(A1[c], w, af1, 0, 0, 0);
          w = wg[c * 64];
          ag0 = __builtin_amdgcn_mfma_f32_16x16x32_bf16(A0[c], w, ag0, 0, 0, 0);
          ag1 = __builtin_amdgcn_mfma_f32_16x16x32_bf16(A1[c], w, ag1, 0, 0, 0);
          w = wo[c * 64];
          ao0 = __builtin_amdgcn_mfma_f32_16x16x32_bf16(A0[c], w, ao0, 0, 0, 0);
          ao1 = __builtin_amdgcn_mfma_f32_16x16x32_bf16(A1[c], w, ao1, 0, 0, 0);
        }
        int u = ut * 16 + n16;
        bool live = (u < HDIM);
#pragma unroll
        for (int mt = 0; mt < 2; ++mt) {
#pragma unroll
          for (int r = 0; r < 4; ++r) {
            int m = mt * 16 + qd * 4 + r;
            float gi = sigm(mt ? ai1[r] : ai0[r]);
            float gf = sigm(mt ? af1[r] : af0[r]);
            float gg = tanh_(mt ? ag1[r] : ag0[r]);
            float go = sigm(mt ? ao1[r] : ao0[r]);
            float cp = c1s[m][u];
            float cn = gf * cp + gi * gg;
            float hn = go * tanh_(cn);
            if (live) {
              c1s[m][u] = cn;
              x2[m][u] = f2bf(hn);  // h1 -> LSTM2 input (own slice)
            }
          }
        }
      }
    }
    __syncthreads();
    // ---- sync1: exchange h1; build x2[0:200] full + x1[48:248] for next step ----
    {
      int u0 = role ? 112 : 0, u1 = role ? 200 : 112;
      int W = (u1 - u0) >> 1;
      for (int i = tid; i < MROWS * W; i += 512) {
        int m = i / W, u = u0 + ((i - m * W) << 1);
        uint32_t v = *(const uint32_t*)&x2[m][u];
        __hip_atomic_store(&h1s[(size_t)(grp * 32 + m) * 104 + (u >> 1)], v,
                           __ATOMIC_RELAXED, __HIP_MEMORY_SCOPE_AGENT);
      }
    }
    ++sctr;
    __syncthreads();
    if (tid == 0) __hip_atomic_store(&flags[bid], sctr, __ATOMIC_RELEASE, __HIP_MEMORY_SCOPE_AGENT);
    while (__hip_atomic_load(&flags[peer], __ATOMIC_ACQUIRE, __HIP_MEMORY_SCOPE_AGENT) < sctr)
      __builtin_amdgcn_s_sleep(2);
    {
      int pu0 = role ? 0 : 112, pu1 = role ? 112 : 200;
      for (int i = tid; i < MROWS * 100; i += 512) {
        int m = i / 100, u = (i - m * 100) << 1;
        uint32_t v;
        if (u >= pu0 && u < pu1) {
          v = __hip_atomic_load(&h1s[(size_t)(grp * 32 + m) * 104 + (u >> 1)],
                                __ATOMIC_RELAXED, __HIP_MEMORY_SCOPE_AGENT);
          *(uint32_t*)&x2[m][u] = v;
        } else {
          v = *(const uint32_t*)&x2[m][u];
        }
        *(uint32_t*)&x1[m][FDIM + u] = v;  // h1 for next step's LSTM1
      }
    }
    __syncthreads();

    // ================= Phase B: LSTM2 (own tiles), K=448 =================
    {
      int ut = l2_lo + wv;
      if (ut < l2_hi) {
        short8 A0[14], A1[14];
#pragma unroll
        for (int c = 0; c < 14; ++c) {
          A0[c] = *(const short8*)&x2[n16][c * 32 + qd * 8];
          A1[c] = *(const short8*)&x2[16 + n16][c * 32 + qd * 8];
        }
        floatx4 ai0, ai1, af0, af1, ag0, ag1, ao0, ao1;
        {
          float b = b2[(0 * 13 + ut) * 16 + n16]; ai0 = {b, b, b, b}; ai1 = ai0;
          b = b2[(1 * 13 + ut) * 16 + n16]; af0 = {b, b, b, b}; af1 = af0;
          b = b2[(2 * 13 + ut) * 16 + n16]; ag0 = {b, b, b, b}; ag1 = ag0;
          b = b2[(3 * 13 + ut) * 16 + n16]; ao0 = {b, b, b, b}; ao1 = ao0;
        }
        const short8* wi = (const short8*)W2p + (size_t)(0 * 13 + ut) * 14 * 64 + lane;
        const short8* wf = (const short8*)W2p + (size_t)(1 * 13 + ut) * 14 * 64 + lane;
        const short8* wg = (const short8*)W2p + (size_t)(2 * 13 + ut) * 14 * 64 + lane;
        const short8* wo = (const short8*)W2p + (size_t)(3 * 13 + ut) * 14 * 64 + lane;
#pragma unroll
        for (int c = 0; c < 14; ++c) {
          short8 w = wi[c * 64];
          ai0 = __builtin_amdgcn_mfma_f32_16x16x32_bf16(A0[c], w, ai0, 0, 0, 0);
          ai1 = __builtin_amdgcn_mfma_f32_16x16x32_bf16(A1[c], w, ai1, 0, 0, 0);
          w = wf[c * 64];
          af0 = __builtin_amdgcn_mfma_f32_16x16x32_bf16(A0[c], w, af0, 0, 0, 0);
          af1 = __builtin_amdgcn_mfma_f32_16x16x32_bf16(A1[c], w, af1, 0, 0, 0);
          w = wg[c * 64];
          ag0 = __builtin_amdgcn_mfma_f32_16x16x32_bf16(A0[c], w, ag0, 0, 0, 0);
          ag1 = __builtin_amdgcn_mfma_f32_16x16x32_bf16(A1[c], w, ag1, 0, 0, 0);
          w = wo[c * 64];
          ao0 = __builtin_amdgcn_mfma_f32_16x16x32_bf16(A0[c], w, ao0, 0, 0, 0);
          ao1 = __builtin_amdgcn_mfma_f32_16x16x32_bf16(A1[c], w, ao1, 0, 0, 0);
        }
        int u = ut * 16 + n16;
        bool live = (u < HDIM);
#pragma unroll
        for (int mt = 0; mt < 2; ++mt) {
#pragma unroll
          for (int r = 0; r < 4; ++r) {
            int m = mt * 16 + qd * 4 + r;
            float gi = sigm(mt ? ai1[r] : ai0[r]);
            float gf = sigm(mt ? af1[r] : af0[r]);
            float gg = tanh_(mt ? ag1[r] : ag0[r]);
            float go = sigm(mt ? ao1[r] : ao0[r]);
            float cp = c2s[m][u];
            float cn = gf * cp + gi * gg;
            float hn = go * tanh_(cn);
            if (live) {
              c2s[m][u] = cn;
              x3[m][u] = f2bf(hn);  // h2 -> FC1 input (own slice)
            }
          }
        }
      }
    }
    __syncthreads();
    // ---- sync2: exchange h2; build x3[0:200] full + x2[248:448] for next step ----
    {
      int u0 = role ? 96 : 0, u1 = role ? 200 : 96;
      int W = (u1 - u0) >> 1;
      for (int i = tid; i < MROWS * W; i += 512) {
        int m = i / W, u = u0 + ((i - m * W) << 1);
        uint32_t v = *(const uint32_t*)&x3[m][u];
        __hip_atomic_store(&h2s[(size_t)(grp * 32 + m) * 104 + (u >> 1)], v,
                           __ATOMIC_RELAXED, __HIP_MEMORY_SCOPE_AGENT);
      }
    }
    ++sctr;
    __syncthreads();
    if (tid == 0) __hip_atomic_store(&flags[bid], sctr, __ATOMIC_RELEASE, __HIP_MEMORY_SCOPE_AGENT);
    while (__hip_atomic_load(&flags[peer], __ATOMIC_ACQUIRE, __HIP_MEMORY_SCOPE_AGENT) < sctr)
      __builtin_amdgcn_s_sleep(2);
    {
      int pu0 = role ? 0 : 96, pu1 = role ? 96 : 200;
      for (int i = tid; i < MROWS * 100; i += 512) {
        int m = i / 100, u = (i - m * 100) << 1;
        uint32_t v;
        if (u >= pu0 && u < pu1) {
          v = __hip_atomic_load(&h2s[(size_t)(grp * 32 + m) * 104 + (u >> 1)],
                                __ATOMIC_RELAXED, __HIP_MEMORY_SCOPE_AGENT);
          *(uint32_t*)&x3[m][u] = v;
        } else {
          v = *(const uint32_t*)&x3[m][u];
        }
        *(uint32_t*)&x2[m][248 + u] = v;  // h2 for next step's LSTM2
      }
    }
    __syncthreads();

    if (t >= CTXM1) {
      // ================= Phase C: FC1 (own tiles), K=256 =================
      {
        int nt = f1_lo + wv;
        if (nt < f1_hi) {
          short8 A0[8], A1[8];
#pragma unroll
          for (int c = 0; c < 8; ++c) {
            A0[c] = *(const short8*)&x3[n16][c * 32 + qd * 8];
            A1[c] = *(const short8*)&x3[16 + n16][c * 32 + qd * 8];
          }
          float bb = b3[nt * 16 + n16];
          floatx4 ac0 = {bb, bb, bb, bb}, ac1 = ac0;
          const short8* wp = (const short8*)W3p + (size_t)nt * 8 * 64 + lane;
#pragma unroll
          for (int c = 0; c < 8; ++c) {
            short8 w = wp[c * 64];
            ac0 = __builtin_amdgcn_mfma_f32_16x16x32_bf16(A0[c], w, ac0, 0, 0, 0);
            ac1 = __builtin_amdgcn_mfma_f32_16x16x32_bf16(A1[c], w, ac1, 0, 0, 0);
          }
          int col = nt * 16 + n16;
#pragma unroll
          for (int r = 0; r < 4; ++r) {
            x4[qd * 4 + r][col] = f2bf(tanh_(ac0[r]));
            x4[16 + qd * 4 + r][col] = f2bf(tanh_(ac1[r]));
          }
        }
      }
      __syncthreads();
      // ---- sync3: exchange out3 -> full x4[0:208] ----
      {
        int u0 = role ? 112 : 0, u1 = role ? 208 : 112;
        int W = (u1 - u0) >> 1;
        for (int i = tid; i < MROWS * W; i += 512) {
          int m = i / W, u = u0 + ((i - m * W) << 1);
          uint32_t v = *(const uint32_t*)&x4[m][u];
          __hip_atomic_store(&o3s[(size_t)(grp * 32 + m) * 104 + (u >> 1)], v,
                             __ATOMIC_RELAXED, __HIP_MEMORY_SCOPE_AGENT);
        }
      }
      ++sctr;
      __syncthreads();
      if (tid == 0) __hip_atomic_store(&flags[bid], sctr, __ATOMIC_RELEASE, __HIP_MEMORY_SCOPE_AGENT);
      while (__hip_atomic_load(&flags[peer], __ATOMIC_ACQUIRE, __HIP_MEMORY_SCOPE_AGENT) < sctr)
        __builtin_amdgcn_s_sleep(2);
      {
        int pu0 = role ? 0 : 112, pu1 = role ? 112 : 208;
        int W = (pu1 - pu0) >> 1;
        for (int i = tid; i < MROWS * W; i += 512) {
          int m = i / W, u = pu0 + ((i - m * W) << 1);
          uint32_t v = __hip_atomic_load(&o3s[(size_t)(grp * 32 + m) * 104 + (u >> 1)],
                                         __ATOMIC_RELAXED, __HIP_MEMORY_SCOPE_AGENT);
          *(uint32_t*)&x4[m][u] = v;
        }
      }
      __syncthreads();
      // ================= Phase D: FC2 (replicated), K=224; waves 3-5 fill tiled =================
      if (wv < 3) {
        int nt = wv;
        short8 A0[7], A1[7];
#pragma unroll
        for (int c = 0; c < 7; ++c) {
          A0[c] = *(const short8*)&x4[n16][c * 32 + qd * 8];
          A1[c] = *(const short8*)&x4[16 + n16][c * 32 + qd * 8];
        }
        float bb = b4[nt * 16 + n16];
        floatx4 ac0 = {bb, bb, bb, bb}, ac1 = ac0;
        const short8* wp = (const short8*)W4p + (size_t)nt * 7 * 64 + lane;
#pragma unroll
        for (int c = 0; c < 7; ++c) {
          short8 w = wp[c * 64];
          ac0 = __builtin_amdgcn_mfma_f32_16x16x32_bf16(A0[c], w, ac0, 0, 0, 0);
          ac1 = __builtin_amdgcn_mfma_f32_16x16x32_bf16(A1[c], w, ac1, 0, 0, 0);
        }
        int col = nt * 16 + n16;
#pragma unroll
        for (int mt = 0; mt < 2; ++mt) {
#pragma unroll
          for (int r = 0; r < 4; ++r) {
            int m = mt * 16 + qd * 4 + r;
            float of = tanh_(mt ? ac1[r] : ac0[r]);
            if ((m >> 4) == role)
              out[((size_t)(t - CTXM1) * BTOT + row0 + m) * FDIM + col] = of;
            if (t < NSTEP - 1) {
              unsigned short bv = f2bf(of);
              x1[m][col] = bv;         // next inp (closed loop)
              x3[m][HDIM + col] = bv;
            }
          }
        }
      }
    } else {
      // ---- D': inp(t+1) = tact[t+1] on waves 0-2 ----
      if (wv < 3) {
        for (int i = wv * 64 + lane; i < MROWS * 12; i += 192) {
          int r = i / 12, f0 = (i % 12) * 4;
          const float* src = &tact[((size_t)(t + 1) * BTOT + row0 + r) * FDIM + f0];
#pragma unroll
          for (int j = 0; j < 4; ++j) {
            unsigned short v = f2bf(src[j]);
            x1[r][f0 + j] = v;
            x3[r][HDIM + f0 + j] = v;
          }
        }
      }
    }
    // ---- tiled(t+1) fill on waves 3-5 ----
    if (wv >= 3 && wv < 6 && t < NSTEP - 1) {
      for (int i = (wv - 3) * 64 + lane; i < MROWS * 12; i += 192) {
        int r = i / 12, a = i % 12;
        float vf = (a < ADIM) ? acts[((size_t)(t + 2) * BTOT + row0 + r) * ADIM + a]
                              : acts[((size_t)(row0 + r)) * ADIM + (a - ADIM)];
        unsigned short v = f2bf(vf);
        unsigned short* d = &x2[r][HDIM];
        d[a] = v; d[12 + a] = v; d[24 + a] = v; d[36 + a] = v;
      }
    }
    __syncthreads();
  }
}

extern "C" void kernel_launch(void* const* d_in, const int* in_sizes, int n_in,
                              void* d_out, int out_size, void* d_ws, size_t ws_size,
                              hipStream_t stream) {
  const float* tact = (const float*)d_in[0];
  const float* acts = (const float*)d_in[1];
  const float* Wih1 = (const float*)d_in[2];
  const float* Whh1 = (const float*)d_in[3];
  const float* bih1 = (const float*)d_in[4];
  const float* bhh1 = (const float*)d_in[5];
  const float* Wih2 = (const float*)d_in[6];
  const float* Whh2 = (const float*)d_in[7];
  const float* bih2 = (const float*)d_in[8];
  const float* bhh2 = (const float*)d_in[9];
  const float* fc1w = (const float*)d_in[10];
  const float* fc1b = (const float*)d_in[11];
  const float* fc2w = (const float*)d_in[12];
  const float* fc2b = (const float*)d_in[13];

  uint8_t* ws = (uint8_t*)d_ws;
  unsigned short* W1p = (unsigned short*)(ws + OFF_W1P);
  unsigned short* W2p = (unsigned short*)(ws + OFF_W2P);
  unsigned short* W3p = (unsigned short*)(ws + OFF_W3P);
  unsigned short* W4p = (unsigned short*)(ws + OFF_W4P);
  float* b1 = (float*)(ws + OFF_B1);
  float* b2 = (float*)(ws + OFF_B2);
  float* b3 = (float*)(ws + OFF_B3);
  float* b4 = (float*)(ws + OFF_B4);
  int* flags = (int*)(ws + OFF_FLG);
  uint32_t* h1s = (uint32_t*)(ws + OFF_H1S);
  uint32_t* h2s = (uint32_t*)(ws + OFF_H2S);
  uint32_t* o3s = (uint32_t*)(ws + OFF_O3S);

  hipLaunchKernelGGL(actp_pack, dim3(326), dim3(256), 0, stream,
                     Wih1, Whh1, bih1, bhh1, Wih2, Whh2, bih2, bhh2,
                     fc1w, fc1b, fc2w, fc2b, W1p, W2p, W3p, W4p, b1, b2, b3, b4, flags);
  hipLaunchKernelGGL(actp_main, dim3(256), dim3(512), 0, stream,
                     tact, acts, W1p, W2p, W3p, W4p, b1, b2, b3, b4,
                     flags, h1s, h2s, o3s, (float*)d_out);
}

// Round 5
// 4143.825 us; speedup vs baseline: 2.7282x; 2.7282x over previous
//
#include <hip/hip_runtime.h>
#include <stdint.h>
#include <stddef.h>

#define HDIM 200
#define FDIM 48
#define ADIM 6
#define BTOT 4096
#define NSTEP 119
#define CTXM1 9   // CONTEXT_FRAMES-1
#define MROWS 16  // batch rows per block

typedef __attribute__((ext_vector_type(8))) short short8;
typedef __attribute__((ext_vector_type(4))) float floatx4;

// soft barrier: drain LDS ops only, leave global loads/stores in flight
#define SOFTBAR() asm volatile("s_waitcnt lgkmcnt(0)\n\ts_barrier" ::: "memory")

// ws layout (bytes) — gate-major packed weights, N padded to 832 (= 4*208)
#define OFF_W1P 0u        // 52*8*64*8 u16
#define OFF_W2P 425984u   // 52*14*64*8 u16
#define OFF_W3P 1171456u  // 13*8*64*8 u16
#define OFF_W4P 1277952u  // 3*7*64*8 u16
#define OFF_B1  1299456u  // 832 f32
#define OFF_B2  1302784u
#define OFF_B3  1306112u  // 208 f32
#define OFF_B4  1306944u  // 48 f32

__device__ __forceinline__ unsigned short f2bf(float f) {
  unsigned int u = __float_as_uint(f);
  u += 0x7FFFu + ((u >> 16) & 1u);
  return (unsigned short)(u >> 16);
}
__device__ __forceinline__ float sigm(float x) { return 1.0f / (1.0f + __expf(-x)); }
__device__ __forceinline__ float tanh_(float x) { return 1.0f - 2.0f / (1.0f + __expf(2.0f * x)); }

// ---------------- weight/bias packing (fp32 -> bf16, gate-major) ----------------
// Packed B-fragment layout: idx = ((tile*nchunk + chunk)*64 + lane)*8 + j
//   value = Wcat[tile*16 + (lane&15)][chunk*32 + (lane>>4)*8 + j]
// LSTM packed row p = gate*208 + u (gate 0..3 = i,f,g,o; pad u>=200 -> 0)
__global__ void actp_pack(
    const float* __restrict__ Wih1, const float* __restrict__ Whh1,
    const float* __restrict__ bih1, const float* __restrict__ bhh1,
    const float* __restrict__ Wih2, const float* __restrict__ Whh2,
    const float* __restrict__ bih2, const float* __restrict__ bhh2,
    const float* __restrict__ fc1w, const float* __restrict__ fc1b,
    const float* __restrict__ fc2w, const float* __restrict__ fc2b,
    unsigned short* __restrict__ W1p, unsigned short* __restrict__ W2p,
    unsigned short* __restrict__ W3p, unsigned short* __restrict__ W4p,
    float* __restrict__ b1, float* __restrict__ b2,
    float* __restrict__ b3, float* __restrict__ b4) {
  int g = blockIdx.x * blockDim.x + threadIdx.x;
  if (g < 26624) {  // W1p: K=256 (inp 48 | h1 200 | pad 8), 8 chunks, 52 tiles
    int lane = g & 63, tc = g >> 6;
    int chunk = tc & 7, tile = tc >> 3;
    int p = tile * 16 + (lane & 15);
    int gate = p / 208, u = p - gate * 208;
    int srow = gate * 200 + u;
    int kb = chunk * 32 + (lane >> 4) * 8;
    unsigned short* d = W1p + (size_t)g * 8;
#pragma unroll
    for (int j = 0; j < 8; ++j) {
      int k = kb + j;
      float v = 0.f;
      if (u < 200) {
        if (k < 48) v = Wih1[srow * 48 + k];
        else if (k < 248) v = Whh1[srow * 200 + (k - 48)];
      }
      d[j] = f2bf(v);
    }
  } else if (g < 73216) {  // W2p: K=448 (h1|tiled|h2), 14 chunks, 52 tiles
    int g2 = g - 26624;
    int lane = g2 & 63, tc = g2 >> 6;
    int chunk = tc % 14, tile = tc / 14;
    int p = tile * 16 + (lane & 15);
    int gate = p / 208, u = p - gate * 208;
    int srow = gate * 200 + u;
    int kb = chunk * 32 + (lane >> 4) * 8;
    unsigned short* d = W2p + (size_t)g2 * 8;
#pragma unroll
    for (int j = 0; j < 8; ++j) {
      int k = kb + j;
      float v = 0.f;
      if (u < 200) v = (k < 248) ? Wih2[srow * 248 + k] : Whh2[srow * 200 + (k - 248)];
      d[j] = f2bf(v);
    }
  } else if (g < 79872) {  // W3p: fc1_w N 200->208, K 248->256
    int g3 = g - 73216;
    int lane = g3 & 63, tc = g3 >> 6;
    int chunk = tc & 7, tile = tc >> 3;
    int p = tile * 16 + (lane & 15);
    int kb = chunk * 32 + (lane >> 4) * 8;
    unsigned short* d = W3p + (size_t)g3 * 8;
#pragma unroll
    for (int j = 0; j < 8; ++j) {
      int k = kb + j;
      float v = (p < 200 && k < 248) ? fc1w[p * 248 + k] : 0.f;
      d[j] = f2bf(v);
    }
  } else if (g < 81216) {  // W4p: fc2_w N=48, K 200->224
    int g4 = g - 79872;
    int lane = g4 & 63, tc = g4 >> 6;
    int chunk = tc % 7, tile = tc / 7;
    int p = tile * 16 + (lane & 15);
    int kb = chunk * 32 + (lane >> 4) * 8;
    unsigned short* d = W4p + (size_t)g4 * 8;
#pragma unroll
    for (int j = 0; j < 8; ++j) {
      int k = kb + j;
      float v = (k < 200) ? fc2w[p * 200 + k] : 0.f;
      d[j] = f2bf(v);
    }
  } else if (g < 83136) {  // biases, gate-major padded
    int i = g - 81216;
    if (i < 832) {
      int gate = i / 208, u = i - gate * 208;
      b1[i] = (u < 200) ? (bih1[gate * 200 + u] + bhh1[gate * 200 + u]) : 0.f;
    } else if (i < 1664) {
      int p = i - 832;
      int gate = p / 208, u = p - gate * 208;
      b2[p] = (u < 200) ? (bih2[gate * 200 + u] + bhh2[gate * 200 + u]) : 0.f;
    } else if (i < 1872) {
      int p = i - 1664;
      b3[p] = (p < 200) ? fc1b[p] : 0.f;
    } else {
      int p = i - 1872;
      b4[p] = fc2b[p];
    }
  }
}

// ---------------- main persistent kernel ----------------
// 256 blocks x 1024 threads (16 waves, 1 block/CU). Block owns rows [16*bid, +16).
// GEMM phases use waves 0-12 (1 unit-tile each); waves 13-15 do next-step fills
// during phase A. Soft barriers keep the L2 weight stream flowing across phases.
__global__ __launch_bounds__(1024, 4) void actp_main(
    const float* __restrict__ tact,   // T*B*F fp32
    const float* __restrict__ acts,   // T*B*A fp32
    const unsigned short* __restrict__ W1p, const unsigned short* __restrict__ W2p,
    const unsigned short* __restrict__ W3p, const unsigned short* __restrict__ W4p,
    const float* __restrict__ b1, const float* __restrict__ b2,
    const float* __restrict__ b3, const float* __restrict__ b4,
    float* __restrict__ out)          // 110*B*F fp32
{
  __shared__ unsigned short x1[2][MROWS][264];  // [inp 0:48 | h1 48:248 | pad]
  __shared__ unsigned short x2[2][MROWS][456];  // [h1 0:200 | tiled 200:248 | h2 248:448]
  __shared__ unsigned short x3[MROWS][264];     // [h2 0:200 | inp 200:248 | pad]
  __shared__ unsigned short x4[MROWS][232];     // [out3 0:208 | pad]
  __shared__ float c1s[MROWS][228];             // stride 228 = 4 mod 32 -> 2-way (free)
  __shared__ float c2s[MROWS][228];

  const int tid = threadIdx.x;
  const int wv = tid >> 6;
  const int lane = tid & 63;
  const int n16 = lane & 15;
  const int qd = lane >> 4;
  const int row0 = (int)blockIdx.x * MROWS;

  // ---- hoisted per-wave constants (biases + weight fragment base pointers) ----
  const int uw = (wv < 13) ? wv : 0;
  float b1g[4], b2g[4];
#pragma unroll
  for (int g = 0; g < 4; ++g) {
    b1g[g] = b1[(g * 13 + uw) * 16 + n16];
    b2g[g] = b2[(g * 13 + uw) * 16 + n16];
  }
  const float b3s = b3[uw * 16 + n16];
  const float b4s = b4[((wv < 3) ? wv : 0) * 16 + n16];
  const short8* w1b[4];
  const short8* w2b[4];
#pragma unroll
  for (int g = 0; g < 4; ++g) {
    w1b[g] = (const short8*)W1p + (size_t)(g * 13 + uw) * 8 * 64 + lane;
    w2b[g] = (const short8*)W2p + (size_t)(g * 13 + uw) * 14 * 64 + lane;
  }
  const short8* w3p = (const short8*)W3p + (size_t)uw * 8 * 64 + lane;
  const short8* w4p = (const short8*)W4p + (size_t)((wv < 3) ? wv : 0) * 7 * 64 + lane;

  // ---- init: zero LDS, fill step-0 inputs ----
  for (int i = tid; i < 2 * MROWS * 264; i += 1024) (&x1[0][0][0])[i] = 0;
  for (int i = tid; i < 2 * MROWS * 456; i += 1024) (&x2[0][0][0])[i] = 0;
  for (int i = tid; i < MROWS * 264; i += 1024) (&x3[0][0])[i] = 0;
  for (int i = tid; i < MROWS * 232; i += 1024) (&x4[0][0])[i] = 0;
  for (int i = tid; i < MROWS * 228; i += 1024) { (&c1s[0][0])[i] = 0.f; (&c2s[0][0])[i] = 0.f; }
  if (tid < 192) {  // inp(0) = tact[0]
    int r = tid / 12, f0 = (tid % 12) * 4;
    const float* src = &tact[((size_t)(row0 + r)) * FDIM + f0];
#pragma unroll
    for (int j = 0; j < 4; ++j) {
      unsigned short v = f2bf(src[j]);
      x1[0][r][f0 + j] = v;
      x3[r][HDIM + f0 + j] = v;
    }
  } else if (tid < 384) {  // tiled(0) = tile([acts[1]|acts[0]], 4)
    int idx = tid - 192;
    int r = idx / 12, a = idx % 12;
    float vf = (a < ADIM) ? acts[((size_t)BTOT + row0 + r) * ADIM + a]
                          : acts[((size_t)(row0 + r)) * ADIM + (a - ADIM)];
    unsigned short v = f2bf(vf);
    unsigned short* d = &x2[0][r][HDIM];
    d[a] = v; d[12 + a] = v; d[24 + a] = v; d[36 + a] = v;
  }
  __syncthreads();

  for (int t = 0; t < NSTEP; ++t) {
    const int cur = t & 1, nxt = cur ^ 1;

    // ========== Phase A: LSTM1 on waves 0-12 (1 ut each); fills on 13-15 ==========
    if (wv < 13) {
      short8 A0[8];
#pragma unroll
      for (int c = 0; c < 8; ++c) A0[c] = *(const short8*)&x1[cur][n16][c * 32 + qd * 8];
      floatx4 ai = {b1g[0], b1g[0], b1g[0], b1g[0]};
      floatx4 af = {b1g[1], b1g[1], b1g[1], b1g[1]};
      floatx4 ag = {b1g[2], b1g[2], b1g[2], b1g[2]};
      floatx4 ao = {b1g[3], b1g[3], b1g[3], b1g[3]};
#pragma unroll
      for (int c = 0; c < 8; ++c) {
        ai = __builtin_amdgcn_mfma_f32_16x16x32_bf16(A0[c], w1b[0][c * 64], ai, 0, 0, 0);
        af = __builtin_amdgcn_mfma_f32_16x16x32_bf16(A0[c], w1b[1][c * 64], af, 0, 0, 0);
        ag = __builtin_amdgcn_mfma_f32_16x16x32_bf16(A0[c], w1b[2][c * 64], ag, 0, 0, 0);
        ao = __builtin_amdgcn_mfma_f32_16x16x32_bf16(A0[c], w1b[3][c * 64], ao, 0, 0, 0);
      }
      int u = wv * 16 + n16;
      bool live = (u < HDIM);
#pragma unroll
      for (int r = 0; r < 4; ++r) {
        int m = qd * 4 + r;
        float gi = sigm(ai[r]), gf = sigm(af[r]);
        float gg = tanh_(ag[r]), go = sigm(ao[r]);
        float cp = c1s[m][u];
        float cn = gf * cp + gi * gg;
        float hn = go * tanh_(cn);
        if (live) {
          c1s[m][u] = cn;
          unsigned short hb = f2bf(hn);
          x2[cur][m][u] = hb;          // LSTM2 input this step
          x1[nxt][m][FDIM + u] = hb;   // LSTM1 input next step
        }
      }
    } else if (wv == 13) {  // tiled(t+1) = tile([acts[t+2]|acts[0]], 4)
      if (t < NSTEP - 1) {
        for (int i = lane; i < MROWS * 12; i += 64) {
          int r = i / 12, a = i % 12;
          float vf = (a < ADIM) ? acts[((size_t)(t + 2) * BTOT + row0 + r) * ADIM + a]
                                : acts[((size_t)(row0 + r)) * ADIM + (a - ADIM)];
          unsigned short v = f2bf(vf);
          unsigned short* d = &x2[nxt][r][HDIM];
          d[a] = v; d[12 + a] = v; d[24 + a] = v; d[36 + a] = v;
        }
      }
    } else {  // wv 14-15: inp(t+1) = tact[t+1] while still in context
      if (t < CTXM1) {
        for (int i = (wv - 14) * 64 + lane; i < MROWS * 12; i += 128) {
          int r = i / 12, f0 = (i % 12) * 4;
          const float* src = &tact[((size_t)(t + 1) * BTOT + row0 + r) * FDIM + f0];
#pragma unroll
          for (int j = 0; j < 4; ++j) {
            unsigned short v = f2bf(src[j]);
            x1[nxt][r][f0 + j] = v;
            x3[r][HDIM + f0 + j] = v;
          }
        }
      }
    }
    SOFTBAR();

    // ========== Phase B: LSTM2 on waves 0-12 (1 ut each), K=448 ==========
    if (wv < 13) {
      short8 A0[14];
#pragma unroll
      for (int c = 0; c < 14; ++c) A0[c] = *(const short8*)&x2[cur][n16][c * 32 + qd * 8];
      floatx4 ai = {b2g[0], b2g[0], b2g[0], b2g[0]};
      floatx4 af = {b2g[1], b2g[1], b2g[1], b2g[1]};
      floatx4 ag = {b2g[2], b2g[2], b2g[2], b2g[2]};
      floatx4 ao = {b2g[3], b2g[3], b2g[3], b2g[3]};
#pragma unroll
      for (int c = 0; c < 14; ++c) {
        ai = __builtin_amdgcn_mfma_f32_16x16x32_bf16(A0[c], w2b[0][c * 64], ai, 0, 0, 0);
        af = __builtin_amdgcn_mfma_f32_16x16x32_bf16(A0[c], w2b[1][c * 64], af, 0, 0, 0);
        ag = __builtin_amdgcn_mfma_f32_16x16x32_bf16(A0[c], w2b[2][c * 64], ag, 0, 0, 0);
        ao = __builtin_amdgcn_mfma_f32_16x16x32_bf16(A0[c], w2b[3][c * 64], ao, 0, 0, 0);
      }
      int u = wv * 16 + n16;
      bool live = (u < HDIM);
#pragma unroll
      for (int r = 0; r < 4; ++r) {
        int m = qd * 4 + r;
        float gi = sigm(ai[r]), gf = sigm(af[r]);
        float gg = tanh_(ag[r]), go = sigm(ao[r]);
        float cp = c2s[m][u];
        float cn = gf * cp + gi * gg;
        float hn = go * tanh_(cn);
        if (live) {
          c2s[m][u] = cn;
          unsigned short hb = f2bf(hn);
          x3[m][u] = hb;               // FC1 input this step
          x2[nxt][m][248 + u] = hb;    // LSTM2 input next step
        }
      }
    }
    SOFTBAR();

    if (t >= CTXM1) {
      // ========== Phase C: FC1 on waves 0-12 (1 nt each), K=256 ==========
      if (wv < 13) {
        short8 A0[8];
#pragma unroll
        for (int c = 0; c < 8; ++c) A0[c] = *(const short8*)&x3[n16][c * 32 + qd * 8];
        floatx4 ac = {b3s, b3s, b3s, b3s};
#pragma unroll
        for (int c = 0; c < 8; ++c)
          ac = __builtin_amdgcn_mfma_f32_16x16x32_bf16(A0[c], w3p[c * 64], ac, 0, 0, 0);
        int col = wv * 16 + n16;
#pragma unroll
        for (int r = 0; r < 4; ++r) x4[qd * 4 + r][col] = f2bf(tanh_(ac[r]));
      }
      SOFTBAR();
      // ========== Phase D: FC2 on waves 0-2, K=224 ==========
      if (wv < 3) {
        short8 A0[7];
#pragma unroll
        for (int c = 0; c < 7; ++c) A0[c] = *(const short8*)&x4[n16][c * 32 + qd * 8];
        floatx4 ac = {b4s, b4s, b4s, b4s};
#pragma unroll
        for (int c = 0; c < 7; ++c)
          ac = __builtin_amdgcn_mfma_f32_16x16x32_bf16(A0[c], w4p[c * 64], ac, 0, 0, 0);
        int col = wv * 16 + n16;
#pragma unroll
        for (int r = 0; r < 4; ++r) {
          int m = qd * 4 + r;
          float of = tanh_(ac[r]);
          out[((size_t)(t - CTXM1) * BTOT + row0 + m) * FDIM + col] = of;
          if (t < NSTEP - 1) {
            unsigned short bv = f2bf(of);
            x1[nxt][m][col] = bv;        // closed-loop inp next step
            x3[m][HDIM + col] = bv;
          }
        }
      }
    }
    SOFTBAR();
  }
}

extern "C" void kernel_launch(void* const* d_in, const int* in_sizes, int n_in,
                              void* d_out, int out_size, void* d_ws, size_t ws_size,
                              hipStream_t stream) {
  const float* tact = (const float*)d_in[0];
  const float* acts = (const float*)d_in[1];
  const float* Wih1 = (const float*)d_in[2];
  const float* Whh1 = (const float*)d_in[3];
  const float* bih1 = (const float*)d_in[4];
  const float* bhh1 = (const float*)d_in[5];
  const float* Wih2 = (const float*)d_in[6];
  const float* Whh2 = (const float*)d_in[7];
  const float* bih2 = (const float*)d_in[8];
  const float* bhh2 = (const float*)d_in[9];
  const float* fc1w = (const float*)d_in[10];
  const float* fc1b = (const float*)d_in[11];
  const float* fc2w = (const float*)d_in[12];
  const float* fc2b = (const float*)d_in[13];

  uint8_t* ws = (uint8_t*)d_ws;
  unsigned short* W1p = (unsigned short*)(ws + OFF_W1P);
  unsigned short* W2p = (unsigned short*)(ws + OFF_W2P);
  unsigned short* W3p = (unsigned short*)(ws + OFF_W3P);
  unsigned short* W4p = (unsigned short*)(ws + OFF_W4P);
  float* b1 = (float*)(ws + OFF_B1);
  float* b2 = (float*)(ws + OFF_B2);
  float* b3 = (float*)(ws + OFF_B3);
  float* b4 = (float*)(ws + OFF_B4);

  hipLaunchKernelGGL(actp_pack, dim3(325), dim3(256), 0, stream,
                     Wih1, Whh1, bih1, bhh1, Wih2, Whh2, bih2, bhh2,
                     fc1w, fc1b, fc2w, fc2b, W1p, W2p, W3p, W4p, b1, b2, b3, b4);
  hipLaunchKernelGGL(actp_main, dim3(256), dim3(1024), 0, stream,
                     tact, acts, W1p, W2p, W3p, W4p, b1, b2, b3, b4,
                     (float*)d_out);
}